// Round 6
// baseline (27.693 us; speedup 1.0000x reference)
//
#include <hip/hip_runtime.h>
#include <stdint.h>

#define HH 512
#define WW 512
#define CC 4
#define BB 8
#define NPIX (BB * HH * WW)    // 2097152
#define SLAB 8
#define NBLK (BB * HH / SLAB)  // 512 blocks, one per 8-row slab

// min over 4 packed u8 row-distances, squared (exact integers in fp32)
__device__ __forceinline__ float row_min_sq(uint32_t v) {
    float c0 = (float)(v & 255u);
    float c1 = (float)((v >> 8) & 255u);
    float c2 = (float)((v >> 16) & 255u);
    float c3 = (float)(v >> 24);
    return fminf(fminf(c0 * c0, c1 * c1), fminf(c2 * c2, c3 * c3));
}

// exact zero-byte mask: byte==0 -> that byte becomes 0xFF (no borrow FPs)
__device__ __forceinline__ uint32_t own_mask(uint32_t v) {
    uint32_t z = (~((v & 0x7F7F7F7Fu) + 0x7F7F7F7Fu)) & ~v & 0x80808080u;
    return (z >> 7) * 255u;
}

// ---------------------------------------------------------------------------
// Wave-cooperative 1D row distance scan. Reads only channels 0..2 of the
// one-hot target row (ch3 is implied). Lane l owns columns [8l, 8l+8).
// ---------------------------------------------------------------------------
__device__ __forceinline__ void scan_row(const float* __restrict__ trow,
                                         int lane, uint32_t* __restrict__ ldsrow) {
    const int j0 = lane << 3;
    const size_t CH = (size_t)HH * WW;

    // one-hot: exactly one channel is exactly 1.0f
    int L[8];
    {
        const float4* p0 = reinterpret_cast<const float4*>(trow + j0);
        const float4* p1 = reinterpret_cast<const float4*>(trow + CH + j0);
        const float4* p2 = reinterpret_cast<const float4*>(trow + 2 * CH + j0);
        float4 a0 = p0[0], b0 = p0[1];
        float4 a1 = p1[0], b1 = p1[1];
        float4 a2 = p2[0], b2 = p2[1];
        float t0[8] = {a0.x, a0.y, a0.z, a0.w, b0.x, b0.y, b0.z, b0.w};
        float t1[8] = {a1.x, a1.y, a1.z, a1.w, b1.x, b1.y, b1.z, b1.w};
        float t2[8] = {a2.x, a2.y, a2.z, a2.w, b2.x, b2.y, b2.z, b2.w};
        #pragma unroll
        for (int jj = 0; jj < 8; ++jj)
            L[jj] = (t0[jj] == 1.0f) ? 0 : (t1[jj] == 1.0f) ? 1 : (t2[jj] == 1.0f) ? 2 : 3;
    }

    uint32_t gp[8] = {0, 0, 0, 0, 0, 0, 0, 0};
    #pragma unroll
    for (int c = 0; c < CC; ++c) {
        // left: last feature index <= j (local run + wave prefix max)
        int run = -1000000;
        int lastL[8];
        #pragma unroll
        for (int jj = 0; jj < 8; ++jj) { if (L[jj] == c) run = j0 + jj; lastL[jj] = run; }
        int incl = run;
        #pragma unroll
        for (int d = 1; d < 64; d <<= 1) {
            int up = __shfl_up(incl, (unsigned)d, 64);
            if (lane >= d) incl = max(incl, up);
        }
        int excl = __shfl_up(incl, 1u, 64);
        if (lane == 0) excl = -1000000;

        // right: next feature index >= j (reverse prefix min)
        int nrun = 1000000;
        int nxtL[8];
        #pragma unroll
        for (int jj = 7; jj >= 0; --jj) { if (L[jj] == c) nrun = j0 + jj; nxtL[jj] = nrun; }
        int rincl = nrun;
        #pragma unroll
        for (int d = 1; d < 64; d <<= 1) {
            int dn = __shfl_down(rincl, (unsigned)d, 64);
            if (lane < 64 - d) rincl = min(rincl, dn);
        }
        int rexcl = __shfl_down(rincl, 1u, 64);
        if (lane == 63) rexcl = 1000000;

        #pragma unroll
        for (int jj = 0; jj < 8; ++jj) {
            int last = max(lastL[jj], excl);
            int nxt  = min(nxtL[jj], rexcl);
            int gg = min(min((j0 + jj) - last, nxt - (j0 + jj)), 255); // >255: exp==0 both sides
            gp[jj] |= ((uint32_t)gg) << (c * 8);
        }
    }
    uint4* o = reinterpret_cast<uint4*>(ldsrow + j0);
    o[0] = make_uint4(gp[0], gp[1], gp[2], gp[3]);
    o[1] = make_uint4(gp[4], gp[5], gp[6], gp[7]);
}

// ---------------------------------------------------------------------------
// Slab-fused kernel: 512 threads own 8 output rows. Pred is prefetched into
// registers at entry so both HBM streams overlap phase-1 scan compute.
// Thread layout: rp = tid>>7 owns rows {2rp, 2rp+1}, 4 consecutive px each.
// NO same-address atomics (rounds 2/4: ~16 ns/block serialized RMW).
// ---------------------------------------------------------------------------
__global__ __launch_bounds__(512, 4) void k_fused(const float* __restrict__ pred,
                                                  const float* __restrict__ target,
                                                  float* __restrict__ partial) {
    __shared__ uint32_t gl[12][WW];   // 24 KB; la = absrow - (i0-2)
    __shared__ float red[8];
    __shared__ int sflag;

    const int bid0 = blockIdx.x;
    // bijective XCD-chunked swizzle (512 = 8 XCDs x 64): XCD x owns batch x.
    const int bid = ((bid0 & 7) << 6) | (bid0 >> 3);
    const int b  = bid >> 6;
    const int i0 = (bid & 63) << 3;
    const int tid = threadIdx.x, wid = tid >> 6, lane = tid & 63;
    const size_t CH = (size_t)HH * WW;
    const float* tbase = target + (size_t)b * CC * CH;

    // ---- pred prefetch: rows s0=2rp, s0+1; 4 px at j4 (8x dwordx4) ----
    const int rp = tid >> 7;
    const int s0 = rp << 1;
    const int j4 = (tid & 127) << 2;
    float4 pA[CC], pB[CC];
    {
        const float* pbase = pred + ((size_t)b * CC * HH + (size_t)i0) * WW + j4;
        #pragma unroll
        for (int c = 0; c < CC; ++c) {
            pA[c] = *reinterpret_cast<const float4*>(pbase + ((size_t)c * HH + s0) * WW);
            pB[c] = *reinterpret_cast<const float4*>(pbase + ((size_t)c * HH + s0 + 1) * WW);
        }
    }

    // ---- phase 1: 12 row scans over 8 waves ----
    {
        int r = i0 - 2 + wid;                      // la = wid
        if (r >= 0 && r < HH) scan_row(tbase + (size_t)r * WW, lane, gl[wid]);
        if (wid < 4) {
            int r2 = i0 + 6 + wid;                 // la = 8 + wid
            if (r2 < HH) scan_row(tbase + (size_t)r2 * WW, lane, gl[8 + wid]);
        }
    }
    if (tid == 0) sflag = 0;
    __syncthreads();

    // ---- phase 2: rows s0, s0+1 share the 6-row LDS window ----
    uint4 vv[6];
    #pragma unroll
    for (int t = 0; t < 6; ++t) vv[t] = *reinterpret_cast<const uint4*>(&gl[s0 + t][j4]);

    uint32_t om0[4], om1[4];
    float b0[4], b1[4];
    {
        uint32_t w0[4] = {vv[2].x, vv[2].y, vv[2].z, vv[2].w};   // own row s0 (la=s0+2)
        uint32_t w1[4] = {vv[3].x, vv[3].y, vv[3].z, vv[3].w};   // own row s0+1
        #pragma unroll
        for (int x = 0; x < 4; ++x) {
            om0[x] = own_mask(w0[x]); b0[x] = row_min_sq(w0[x] | om0[x]);
            om1[x] = own_mask(w1[x]); b1[x] = row_min_sq(w1[x] | om1[x]);
        }
    }
    #pragma unroll
    for (int dk = -2; dk <= 2; ++dk) {
        if (dk == 0) continue;
        const float dk2 = (float)(dk * dk);
        if ((unsigned)(i0 + s0 + dk) < (unsigned)HH) {
            const uint4 v = vv[2 + dk];
            uint32_t w[4] = {v.x, v.y, v.z, v.w};
            #pragma unroll
            for (int x = 0; x < 4; ++x) b0[x] = fminf(b0[x], row_min_sq(w[x] | om0[x]) + dk2);
        }
        if ((unsigned)(i0 + s0 + 1 + dk) < (unsigned)HH) {
            const uint4 v = vv[3 + dk];
            uint32_t w[4] = {v.x, v.y, v.z, v.w};
            #pragma unroll
            for (int x = 0; x < 4; ++x) b1[x] = fminf(b1[x], row_min_sq(w[x] | om1[x]) + dk2);
        }
    }

    {
        float mx = 0.f;
        #pragma unroll
        for (int x = 0; x < 4; ++x) mx = fmaxf(mx, fmaxf(b0[x], b1[x]));
        if (__any(mx > 9.0f)) { if (lane == 0) sflag = 1; }
    }
    __syncthreads();

    // ---- rare exact fallback: band rescans reusing gl[0..7] (slot = s) ----
    if (sflag) {
        for (int dk = 3; dk < HH; ++dk) {
            { int rr = i0 + wid - dk;               // up band
              if (rr >= 0 && rr < HH) scan_row(tbase + (size_t)rr * WW, lane, gl[wid]); }
            __syncthreads();
            const float dk2 = (float)(dk * dk);
            if (i0 + s0 - dk >= 0) {
                uint4 v = *reinterpret_cast<const uint4*>(&gl[s0][j4]);
                uint32_t w[4] = {v.x, v.y, v.z, v.w};
                #pragma unroll
                for (int x = 0; x < 4; ++x) b0[x] = fminf(b0[x], row_min_sq(w[x] | om0[x]) + dk2);
            }
            if (i0 + s0 + 1 - dk >= 0) {
                uint4 v = *reinterpret_cast<const uint4*>(&gl[s0 + 1][j4]);
                uint32_t w[4] = {v.x, v.y, v.z, v.w};
                #pragma unroll
                for (int x = 0; x < 4; ++x) b1[x] = fminf(b1[x], row_min_sq(w[x] | om1[x]) + dk2);
            }
            __syncthreads();
            { int rr = i0 + wid + dk;               // down band
              if (rr < HH) scan_row(tbase + (size_t)rr * WW, lane, gl[wid]); }
            __syncthreads();
            if (i0 + s0 + dk < HH) {
                uint4 v = *reinterpret_cast<const uint4*>(&gl[s0][j4]);
                uint32_t w[4] = {v.x, v.y, v.z, v.w};
                #pragma unroll
                for (int x = 0; x < 4; ++x) b0[x] = fminf(b0[x], row_min_sq(w[x] | om0[x]) + dk2);
            }
            if (i0 + s0 + 1 + dk < HH) {
                uint4 v = *reinterpret_cast<const uint4*>(&gl[s0 + 1][j4]);
                uint32_t w[4] = {v.x, v.y, v.z, v.w};
                #pragma unroll
                for (int x = 0; x < 4; ++x) b1[x] = fminf(b1[x], row_min_sq(w[x] | om1[x]) + dk2);
            }
            __syncthreads();
            if (tid == 0) sflag = 0;
            __syncthreads();
            const float nthr = (float)((dk + 1) * (dk + 1));
            float mx = 0.f;
            #pragma unroll
            for (int x = 0; x < 4; ++x) mx = fmaxf(mx, fmaxf(b0[x], b1[x]));
            if (__any(mx > nthr)) { if (lane == 0) sflag = 1; }
            __syncthreads();
            if (!sflag) break;
            if (i0 + SLAB - 1 - dk < 0 && i0 + dk >= HH) break;  // exhausted
        }
    }

    // ---- CE from prefetched pred (label = zero-byte of own g) + weight ----
    float vacc = 0.f;
    #pragma unroll
    for (int x = 0; x < 4; ++x) {
        {
            float a[CC] = {reinterpret_cast<const float*>(&pA[0])[x],
                           reinterpret_cast<const float*>(&pA[1])[x],
                           reinterpret_cast<const float*>(&pA[2])[x],
                           reinterpret_cast<const float*>(&pA[3])[x]};
            const int L = __builtin_ctz(om0[x]) >> 3;   // om != 0 (own dist is 0)
            float m = fmaxf(fmaxf(a[0], a[1]), fmaxf(a[2], a[3]));
            float ssum = __expf(a[0] - m) + __expf(a[1] - m) +
                         __expf(a[2] - m) + __expf(a[3] - m);
            float xs = (L == 0) ? a[0] : (L == 1) ? a[1] : (L == 2) ? a[2] : a[3];
            float pp = (m + __logf(ssum)) - xs;
            vacc += pp * fmaf(10.0f, __expf(-0.02f * b0[x]), 2.0f);
        }
        {
            float a[CC] = {reinterpret_cast<const float*>(&pB[0])[x],
                           reinterpret_cast<const float*>(&pB[1])[x],
                           reinterpret_cast<const float*>(&pB[2])[x],
                           reinterpret_cast<const float*>(&pB[3])[x]};
            const int L = __builtin_ctz(om1[x]) >> 3;
            float m = fmaxf(fmaxf(a[0], a[1]), fmaxf(a[2], a[3]));
            float ssum = __expf(a[0] - m) + __expf(a[1] - m) +
                         __expf(a[2] - m) + __expf(a[3] - m);
            float xs = (L == 0) ? a[0] : (L == 1) ? a[1] : (L == 2) ? a[2] : a[3];
            float pp = (m + __logf(ssum)) - xs;
            vacc += pp * fmaf(10.0f, __expf(-0.02f * b1[x]), 2.0f);
        }
    }

    // ---- block reduction -> partial[] (no atomics) ----
    #pragma unroll
    for (int off = 32; off > 0; off >>= 1) vacc += __shfl_down(vacc, (unsigned)off, 64);
    if (lane == 0) red[wid] = vacc;
    __syncthreads();
    if (tid == 0) {
        float bsum = ((red[0] + red[1]) + (red[2] + red[3]))
                   + ((red[4] + red[5]) + (red[6] + red[7]));
        partial[blockIdx.x] = bsum;
    }
}

// ---------------------------------------------------------------------------
// K_red: deterministic double-precision final reduction over 512 partials.
// ---------------------------------------------------------------------------
__global__ __launch_bounds__(256) void k_red(const float* __restrict__ partial,
                                             float* __restrict__ out) {
    __shared__ double sd[256];
    double a = (double)partial[threadIdx.x] + (double)partial[threadIdx.x + 256];
    sd[threadIdx.x] = a;
    __syncthreads();
    #pragma unroll
    for (int s = 128; s > 0; s >>= 1) {
        if (threadIdx.x < s) sd[threadIdx.x] += sd[threadIdx.x + s];
        __syncthreads();
    }
    if (threadIdx.x == 0) out[0] = (float)(sd[0] * (1.0 / (double)NPIX));
}

extern "C" void kernel_launch(void* const* d_in, const int* in_sizes, int n_in,
                              void* d_out, int out_size, void* d_ws, size_t ws_size,
                              hipStream_t stream) {
    const float* pred   = (const float*)d_in[0];
    const float* target = (const float*)d_in[1];
    float* partial = (float*)d_ws;     // 2 KB
    float* out = (float*)d_out;

    hipLaunchKernelGGL(k_fused, dim3(NBLK), dim3(512), 0, stream, pred, target, partial);
    hipLaunchKernelGGL(k_red, dim3(1), dim3(256), 0, stream, partial, out);
}

// Round 7
// 25.405 us; speedup vs baseline: 1.0900x; 1.0900x over previous
//
#include <hip/hip_runtime.h>
#include <stdint.h>

#define HH 512
#define WW 512
#define CC 4
#define BB 8
#define NPIX (BB * HH * WW)    // 2097152
#define SLAB 8
#define NBLK (BB * HH / SLAB)  // 512 blocks, one per 8-row slab

// min over 4 packed u8 row-distances, squared (exact integers in fp32)
__device__ __forceinline__ float row_min_sq(uint32_t v) {
    float c0 = (float)(v & 255u);
    float c1 = (float)((v >> 8) & 255u);
    float c2 = (float)((v >> 16) & 255u);
    float c3 = (float)(v >> 24);
    return fminf(fminf(c0 * c0, c1 * c1), fminf(c2 * c2, c3 * c3));
}

// exact zero-byte mask: byte==0 -> that byte becomes 0xFF (no borrow FPs)
__device__ __forceinline__ uint32_t own_mask(uint32_t v) {
    uint32_t z = (~((v & 0x7F7F7F7Fu) + 0x7F7F7F7Fu)) & ~v & 0x80808080u;
    return (z >> 7) * 255u;
}

// ---------------------------------------------------------------------------
// Wave-cooperative row worker. Reads 3 of 4 one-hot target channels,
// computes per-class 1D distances -> gl row. If prow != nullptr, also loads
// pred (4 ch) for the SAME row, computes CE = lse - x[label] -> ppl row.
// Fusing CE here keeps pred+target HBM streams concurrently in flight while
// using only per-wave-lifetime registers (round 6 lesson: cross-phase VGPR
// prefetch under a launch_bounds cap spills inside the scan).
// ---------------------------------------------------------------------------
__device__ __forceinline__ void scan_row(const float* __restrict__ trow,
                                         const float* __restrict__ prow,
                                         int lane,
                                         uint32_t* __restrict__ ldsrow,
                                         float* __restrict__ pprow) {
    const int j0 = lane << 3;
    const size_t CH = (size_t)HH * WW;

    // one-hot: exactly one channel is exactly 1.0f
    int L[8];
    {
        const float4* p0 = reinterpret_cast<const float4*>(trow + j0);
        const float4* p1 = reinterpret_cast<const float4*>(trow + CH + j0);
        const float4* p2 = reinterpret_cast<const float4*>(trow + 2 * CH + j0);
        float4 a0 = p0[0], b0 = p0[1];
        float4 a1 = p1[0], b1 = p1[1];
        float4 a2 = p2[0], b2 = p2[1];
        float t0[8] = {a0.x, a0.y, a0.z, a0.w, b0.x, b0.y, b0.z, b0.w};
        float t1[8] = {a1.x, a1.y, a1.z, a1.w, b1.x, b1.y, b1.z, b1.w};
        float t2[8] = {a2.x, a2.y, a2.z, a2.w, b2.x, b2.y, b2.z, b2.w};
        #pragma unroll
        for (int jj = 0; jj < 8; ++jj)
            L[jj] = (t0[jj] == 1.0f) ? 0 : (t1[jj] == 1.0f) ? 1 : (t2[jj] == 1.0f) ? 2 : 3;
    }

    uint32_t gp[8] = {0, 0, 0, 0, 0, 0, 0, 0};
    #pragma unroll
    for (int c = 0; c < CC; ++c) {
        // left: last feature index <= j (local run + wave prefix max)
        int run = -1000000;
        int lastL[8];
        #pragma unroll
        for (int jj = 0; jj < 8; ++jj) { if (L[jj] == c) run = j0 + jj; lastL[jj] = run; }
        int incl = run;
        #pragma unroll
        for (int d = 1; d < 64; d <<= 1) {
            int up = __shfl_up(incl, (unsigned)d, 64);
            if (lane >= d) incl = max(incl, up);
        }
        int excl = __shfl_up(incl, 1u, 64);
        if (lane == 0) excl = -1000000;

        // right: next feature index >= j (reverse prefix min)
        int nrun = 1000000;
        int nxtL[8];
        #pragma unroll
        for (int jj = 7; jj >= 0; --jj) { if (L[jj] == c) nrun = j0 + jj; nxtL[jj] = nrun; }
        int rincl = nrun;
        #pragma unroll
        for (int d = 1; d < 64; d <<= 1) {
            int dn = __shfl_down(rincl, (unsigned)d, 64);
            if (lane < 64 - d) rincl = min(rincl, dn);
        }
        int rexcl = __shfl_down(rincl, 1u, 64);
        if (lane == 63) rexcl = 1000000;

        #pragma unroll
        for (int jj = 0; jj < 8; ++jj) {
            int last = max(lastL[jj], excl);
            int nxt  = min(nxtL[jj], rexcl);
            int gg = min(min((j0 + jj) - last, nxt - (j0 + jj)), 255); // >255: exp==0 both sides
            gp[jj] |= ((uint32_t)gg) << (c * 8);
        }
    }
    uint4* o = reinterpret_cast<uint4*>(ldsrow + j0);
    o[0] = make_uint4(gp[0], gp[1], gp[2], gp[3]);
    o[1] = make_uint4(gp[4], gp[5], gp[6], gp[7]);

    // fused CE for this row (only for owned rows)
    if (prow) {
        float x[CC][8];
        #pragma unroll
        for (int c = 0; c < CC; ++c) {
            const float4* p = reinterpret_cast<const float4*>(prow + (size_t)c * CH + j0);
            float4 a0 = p[0], a1 = p[1];
            x[c][0] = a0.x; x[c][1] = a0.y; x[c][2] = a0.z; x[c][3] = a0.w;
            x[c][4] = a1.x; x[c][5] = a1.y; x[c][6] = a1.z; x[c][7] = a1.w;
        }
        float ppv[8];
        #pragma unroll
        for (int jj = 0; jj < 8; ++jj) {
            float m = fmaxf(fmaxf(x[0][jj], x[1][jj]), fmaxf(x[2][jj], x[3][jj]));
            float s = __expf(x[0][jj] - m) + __expf(x[1][jj] - m) +
                      __expf(x[2][jj] - m) + __expf(x[3][jj] - m);
            float xs = (L[jj] == 0) ? x[0][jj] : (L[jj] == 1) ? x[1][jj]
                     : (L[jj] == 2) ? x[2][jj] : x[3][jj];
            ppv[jj] = (m + __logf(s)) - xs;
        }
        float4* po = reinterpret_cast<float4*>(pprow + j0);
        po[0] = make_float4(ppv[0], ppv[1], ppv[2], ppv[3]);
        po[1] = make_float4(ppv[4], ppv[5], ppv[6], ppv[7]);
    }
}

// ---------------------------------------------------------------------------
// Slab-fused kernel: 512 threads own 8 output rows. Phase 1: 12 target-row
// scans + 8 fused CE rows -> LDS (one continuous memory phase, both HBM
// streams overlapped). Phase 2: pure LDS min-plus (+-2) + weight + reduce.
// NO same-address atomics (rounds 2/4: serialized RMW cost ~10 ns/block).
// ---------------------------------------------------------------------------
__global__ __launch_bounds__(512) void k_fused(const float* __restrict__ pred,
                                               const float* __restrict__ target,
                                               float* __restrict__ partial) {
    __shared__ uint32_t gl[12][WW];   // 24 KB; la = absrow - (i0-2)
    __shared__ float ppl[8][WW];      // 16 KB; CE per owned row
    __shared__ float red[8];
    __shared__ int sflag;

    const int bid0 = blockIdx.x;
    // bijective XCD-chunked swizzle (512 = 8 XCDs x 64): XCD x owns batch x.
    const int bid = ((bid0 & 7) << 6) | (bid0 >> 3);
    const int b  = bid >> 6;
    const int i0 = (bid & 63) << 3;
    const int tid = threadIdx.x, wid = tid >> 6, lane = tid & 63;
    const size_t CH = (size_t)HH * WW;
    const float* tbase = target + (size_t)b * CC * CH;
    const float* pbase = pred   + (size_t)b * CC * CH;

    // ---- phase 1: waves 0..7 scan la=wid; waves 0..3 also la=8+wid.
    //      CE ownership: s=wid-2 for waves 2..7 (1st scan), s=6+wid for
    //      waves 0..1 (2nd scan) -> all 8 owned rows, each exactly once. ----
    {
        int r = i0 - 2 + wid;                      // la = wid
        if (r >= 0 && r < HH) {
            bool ce = (wid >= 2);                  // owned row s = wid-2
            scan_row(tbase + (size_t)r * WW, ce ? pbase + (size_t)r * WW : nullptr,
                     lane, gl[wid], ce ? ppl[wid - 2] : nullptr);
        }
        if (wid < 4) {
            int r2 = i0 + 6 + wid;                 // la = 8 + wid
            if (r2 < HH) {
                bool ce = (wid < 2);               // owned row s = 6 + wid
                scan_row(tbase + (size_t)r2 * WW, ce ? pbase + (size_t)r2 * WW : nullptr,
                         lane, gl[8 + wid], ce ? ppl[6 + wid] : nullptr);
            }
        }
    }
    if (tid == 0) sflag = 0;
    __syncthreads();

    // ---- phase 2: rp = tid>>7 owns rows {2rp, 2rp+1}, 4 px at j4 ----
    const int rp = tid >> 7;
    const int s0 = rp << 1;
    const int j4 = (tid & 127) << 2;

    uint4 vv[6];
    #pragma unroll
    for (int t = 0; t < 6; ++t) vv[t] = *reinterpret_cast<const uint4*>(&gl[s0 + t][j4]);

    uint32_t om0[4], om1[4];
    float b0[4], b1[4];
    {
        uint32_t w0[4] = {vv[2].x, vv[2].y, vv[2].z, vv[2].w};   // own row s0 (la=s0+2)
        uint32_t w1[4] = {vv[3].x, vv[3].y, vv[3].z, vv[3].w};   // own row s0+1
        #pragma unroll
        for (int x = 0; x < 4; ++x) {
            om0[x] = own_mask(w0[x]); b0[x] = row_min_sq(w0[x] | om0[x]);
            om1[x] = own_mask(w1[x]); b1[x] = row_min_sq(w1[x] | om1[x]);
        }
    }
    #pragma unroll
    for (int dk = -2; dk <= 2; ++dk) {
        if (dk == 0) continue;
        const float dk2 = (float)(dk * dk);
        if ((unsigned)(i0 + s0 + dk) < (unsigned)HH) {
            const uint4 v = vv[2 + dk];
            uint32_t w[4] = {v.x, v.y, v.z, v.w};
            #pragma unroll
            for (int x = 0; x < 4; ++x) b0[x] = fminf(b0[x], row_min_sq(w[x] | om0[x]) + dk2);
        }
        if ((unsigned)(i0 + s0 + 1 + dk) < (unsigned)HH) {
            const uint4 v = vv[3 + dk];
            uint32_t w[4] = {v.x, v.y, v.z, v.w};
            #pragma unroll
            for (int x = 0; x < 4; ++x) b1[x] = fminf(b1[x], row_min_sq(w[x] | om1[x]) + dk2);
        }
    }

    {
        float mx = 0.f;
        #pragma unroll
        for (int x = 0; x < 4; ++x) mx = fmaxf(mx, fmaxf(b0[x], b1[x]));
        if (__any(mx > 9.0f)) { if (lane == 0) sflag = 1; }
    }
    __syncthreads();

    // ---- rare exact fallback: band rescans reusing gl[0..7] (slot = s) ----
    if (sflag) {
        for (int dk = 3; dk < HH; ++dk) {
            { int rr = i0 + wid - dk;               // up band
              if (rr >= 0 && rr < HH)
                  scan_row(tbase + (size_t)rr * WW, nullptr, lane, gl[wid], nullptr); }
            __syncthreads();
            const float dk2 = (float)(dk * dk);
            if (i0 + s0 - dk >= 0) {
                uint4 v = *reinterpret_cast<const uint4*>(&gl[s0][j4]);
                uint32_t w[4] = {v.x, v.y, v.z, v.w};
                #pragma unroll
                for (int x = 0; x < 4; ++x) b0[x] = fminf(b0[x], row_min_sq(w[x] | om0[x]) + dk2);
            }
            if (i0 + s0 + 1 - dk >= 0) {
                uint4 v = *reinterpret_cast<const uint4*>(&gl[s0 + 1][j4]);
                uint32_t w[4] = {v.x, v.y, v.z, v.w};
                #pragma unroll
                for (int x = 0; x < 4; ++x) b1[x] = fminf(b1[x], row_min_sq(w[x] | om1[x]) + dk2);
            }
            __syncthreads();
            { int rr = i0 + wid + dk;               // down band
              if (rr < HH)
                  scan_row(tbase + (size_t)rr * WW, nullptr, lane, gl[wid], nullptr); }
            __syncthreads();
            if (i0 + s0 + dk < HH) {
                uint4 v = *reinterpret_cast<const uint4*>(&gl[s0][j4]);
                uint32_t w[4] = {v.x, v.y, v.z, v.w};
                #pragma unroll
                for (int x = 0; x < 4; ++x) b0[x] = fminf(b0[x], row_min_sq(w[x] | om0[x]) + dk2);
            }
            if (i0 + s0 + 1 + dk < HH) {
                uint4 v = *reinterpret_cast<const uint4*>(&gl[s0 + 1][j4]);
                uint32_t w[4] = {v.x, v.y, v.z, v.w};
                #pragma unroll
                for (int x = 0; x < 4; ++x) b1[x] = fminf(b1[x], row_min_sq(w[x] | om1[x]) + dk2);
            }
            __syncthreads();
            if (tid == 0) sflag = 0;
            __syncthreads();
            const float nthr = (float)((dk + 1) * (dk + 1));
            float mx = 0.f;
            #pragma unroll
            for (int x = 0; x < 4; ++x) mx = fmaxf(mx, fmaxf(b0[x], b1[x]));
            if (__any(mx > nthr)) { if (lane == 0) sflag = 1; }
            __syncthreads();
            if (!sflag) break;
            if (i0 + SLAB - 1 - dk < 0 && i0 + dk >= HH) break;  // exhausted
        }
    }

    // ---- weight from LDS CE + block sum ----
    float4 ppA = *reinterpret_cast<const float4*>(&ppl[s0][j4]);
    float4 ppB = *reinterpret_cast<const float4*>(&ppl[s0 + 1][j4]);
    const float pa[4] = {ppA.x, ppA.y, ppA.z, ppA.w};
    const float pb[4] = {ppB.x, ppB.y, ppB.z, ppB.w};
    float vacc = 0.f;
    #pragma unroll
    for (int x = 0; x < 4; ++x) {
        vacc += pa[x] * fmaf(10.0f, __expf(-0.02f * b0[x]), 2.0f);
        vacc += pb[x] * fmaf(10.0f, __expf(-0.02f * b1[x]), 2.0f);
    }

    // ---- block reduction -> partial[] (no atomics) ----
    #pragma unroll
    for (int off = 32; off > 0; off >>= 1) vacc += __shfl_down(vacc, (unsigned)off, 64);
    if (lane == 0) red[wid] = vacc;
    __syncthreads();
    if (tid == 0) {
        float bsum = ((red[0] + red[1]) + (red[2] + red[3]))
                   + ((red[4] + red[5]) + (red[6] + red[7]));
        partial[blockIdx.x] = bsum;
    }
}

// ---------------------------------------------------------------------------
// K_red: deterministic double-precision final reduction over 512 partials.
// ---------------------------------------------------------------------------
__global__ __launch_bounds__(256) void k_red(const float* __restrict__ partial,
                                             float* __restrict__ out) {
    __shared__ double sd[256];
    double a = (double)partial[threadIdx.x] + (double)partial[threadIdx.x + 256];
    sd[threadIdx.x] = a;
    __syncthreads();
    #pragma unroll
    for (int s = 128; s > 0; s >>= 1) {
        if (threadIdx.x < s) sd[threadIdx.x] += sd[threadIdx.x + s];
        __syncthreads();
    }
    if (threadIdx.x == 0) out[0] = (float)(sd[0] * (1.0 / (double)NPIX));
}

extern "C" void kernel_launch(void* const* d_in, const int* in_sizes, int n_in,
                              void* d_out, int out_size, void* d_ws, size_t ws_size,
                              hipStream_t stream) {
    const float* pred   = (const float*)d_in[0];
    const float* target = (const float*)d_in[1];
    float* partial = (float*)d_ws;     // 2 KB
    float* out = (float*)d_out;

    hipLaunchKernelGGL(k_fused, dim3(NBLK), dim3(512), 0, stream, pred, target, partial);
    hipLaunchKernelGGL(k_red, dim3(1), dim3(256), 0, stream, partial, out);
}